// Round 8
// baseline (670.218 us; speedup 1.0000x reference)
//
#include <hip/hip_runtime.h>
#include <hip/hip_cooperative_groups.h>

typedef short bf16x8 __attribute__((ext_vector_type(8)));
typedef float floatx4 __attribute__((ext_vector_type(4)));
typedef float floatx2 __attribute__((ext_vector_type(2)));

typedef const __attribute__((address_space(1))) void* gas_ptr;
typedef __attribute__((address_space(3))) void* las_ptr;

#define EPB  4096   // edges per hist/scatter chunk (16 per thread)
#define MAXB 6144   // bucket capacity (mean 4096, sigma 64 -> 32 sigma headroom)

__device__ __forceinline__ unsigned short f2bf(float f) {
    unsigned int u = __float_as_uint(f);
    unsigned int r = u + 0x7fffu + ((u >> 16) & 1u);   // RNE
    return (unsigned short)(r >> 16);
}

// Async global->LDS 16B: HW writes lbase + lane*16; g is the per-lane source.
__device__ __forceinline__ void stage16(const void* g, void* lbase, int lane) {
#if __has_builtin(__builtin_amdgcn_global_load_lds)
    __builtin_amdgcn_global_load_lds((gas_ptr)g, (las_ptr)lbase, 16, 0, 0);
#else
    *(float4*)((char*)lbase + lane * 16) = *(const float4*)g;
#endif
}

// ---------------------------------------------------------------------------
// The whole 5-kernel prefix as ONE cooperative kernel. Phase bodies are the
// PROVEN round-0 algorithms, each wrapped in a grid-stride loop so any grid
// size is correct. Host sizes the grid from the occupancy query (expected
// ~5 blocks/CU x 256 CU = 1280 -> full machine; round-4 lesson: a coop grid
// of 1 block/CU strangles streaming phases). 5 launches -> 1 launch + 4 grid
// syncs. Fallback: per-phase normal launches (plo==phi -> no sync executed).
//
// ph0: h->bf16 (8 floats/thread) + WT2[c][k] build + per-chunk coarse-bucket
//      (dst>>8) LDS histogram -> gh[bin][chunk] (bin-major, NO global atomics)
// ph1: scan1 over flattened M=nB*nblkH (block sums -> bsum)
// ph2: scan_final -> sgh = global exclusive prefix (bin-major => per-bucket
//      base + within-bucket chunk offsets in one scan)
// ph3: scatter chunks into buckets via LDS cursors (plain sequential stores)
//      tmp packing: src(16) | rel<<16(7) | (dst&255)<<23(8)
// ph4: per-bucket LDS sort by dst&255 -> rowptr + sedge (src<<8 | rel<<25)
// ---------------------------------------------------------------------------
__global__ __launch_bounds__(256) void prefix_pipe(
    const float* __restrict__ h, unsigned short* __restrict__ hbf, int nconv8,
    const int* __restrict__ dst, const int* __restrict__ src,
    const int* __restrict__ rel,
    const float* __restrict__ basis, const float* __restrict__ loopw,
    unsigned short* __restrict__ WT2,
    int* __restrict__ gh, int* __restrict__ bsum, int* __restrict__ sgh,
    unsigned int* __restrict__ tmp, unsigned int* __restrict__ sedge,
    int* __restrict__ rowptr,
    int E, int N, int nB, int nblkH, int M, int NBs, int plo, int phi)
{
    __shared__ unsigned int eb[MAXB];              // 24 KB (ph4)
    __shared__ int sh1[256], sh2[256], sh3[256];   // 3 KB
    const int b = blockIdx.x;
    const int t = threadIdx.x;
    const int G = gridDim.x;

    for (int ph = plo; ph <= phi; ++ph) {
        if (ph == 0) {
            // h -> bf16, 8 floats/thread, grid-stride
            for (int idx = b * 256 + t; idx < nconv8; idx += G * 256) {
                const float4 v0 = *(const float4*)(h + (size_t)idx * 8);
                const float4 v1 = *(const float4*)(h + (size_t)idx * 8 + 4);
                uint4 p;
                p.x = (unsigned int)f2bf(v0.x) | ((unsigned int)f2bf(v0.y) << 16);
                p.y = (unsigned int)f2bf(v0.z) | ((unsigned int)f2bf(v0.w) << 16);
                p.z = (unsigned int)f2bf(v1.x) | ((unsigned int)f2bf(v1.y) << 16);
                p.w = (unsigned int)f2bf(v1.z) | ((unsigned int)f2bf(v1.w) << 16);
                *(uint4*)(hbf + (size_t)idx * 8) = p;
            }
            // WT2[c][k]
            for (int idx = b * 256 + t; idx < 128 * 640; idx += G * 256) {
                const int c = idx / 640, k = idx - c * 640;
                float v = (k < 512) ? basis[(size_t)k * 128 + c]
                                    : loopw[(size_t)(k - 512) * 128 + c];
                WT2[idx] = f2bf(v);
            }
            // per-chunk histogram -> gh[bin][chunk]
            for (int bb = b; bb < nblkH; bb += G) {
                sh1[t] = 0;
                __syncthreads();
                const int cbase = bb * EPB;
#pragma unroll
                for (int j = 0; j < EPB / 256; ++j) {
                    int e = cbase + j * 256 + t;
                    if (e < E) atomicAdd(&sh1[dst[e] >> 8], 1);
                }
                __syncthreads();
                if (t < nB) gh[(size_t)t * nblkH + bb] = sh1[t];
                __syncthreads();
            }
        } else if (ph == 1) {
            for (int blk = b; blk < NBs; blk += G) {
                int i = blk * 256 + t;
                sh1[t] = (i < M) ? gh[i] : 0;
                __syncthreads();
                for (int o = 128; o > 0; o >>= 1) {
                    if (t < o) sh1[t] += sh1[t + o];
                    __syncthreads();
                }
                if (t == 0) bsum[blk] = sh1[0];
                __syncthreads();
            }
        } else if (ph == 2) {
            for (int blk = b; blk < NBs; blk += G) {
                int i = blk * 256 + t;
                sh2[t] = (t < blk) ? bsum[t] : 0;   // NBs <= 256
                int v = (i < M) ? gh[i] : 0;
                sh1[t] = v;
                __syncthreads();
                for (int o = 128; o > 0; o >>= 1) { // reduce sh2 -> block base
                    if (t < o) sh2[t] += sh2[t + o];
                    __syncthreads();
                }
                for (int o = 1; o < 256; o <<= 1) { // inclusive scan of sh1
                    int x = (t >= o) ? sh1[t - o] : 0;
                    __syncthreads();
                    sh1[t] += x;
                    __syncthreads();
                }
                if (i < M) sgh[i] = sh1[t] - v + sh2[0];   // exclusive
                __syncthreads();
            }
        } else if (ph == 3) {
            for (int blk = b; blk < nblkH; blk += G) {
                if (t < nB) sh3[t] = sgh[(size_t)t * nblkH + blk];
                __syncthreads();
                const int cbase = blk * EPB;
#pragma unroll
                for (int j = 0; j < EPB / 256; ++j) {
                    int e = cbase + j * 256 + t;
                    if (e < E) {
                        int d = dst[e];
                        int slot = atomicAdd(&sh3[d >> 8], 1);
                        tmp[slot] = (unsigned int)src[e]
                                  | ((unsigned int)rel[e] << 16)
                                  | ((unsigned int)(d & 255) << 23);
                    }
                }
                __syncthreads();
            }
        } else {                                   // ph == 4: bucket sort
            for (int bb = b; bb < nB; bb += G) {
                const int brow = sgh[(size_t)bb * nblkH];
                const int next = (bb + 1 < nB) ? sgh[(size_t)(bb + 1) * nblkH] : E;
                int n = next - brow;
                if (n > MAXB) n = MAXB;            // statistically unreachable
                sh1[t] = 0;
                __syncthreads();
                for (int i = t; i < n; i += 256) {
                    unsigned int v = tmp[brow + i];
                    eb[i] = v;
                    atomicAdd(&sh1[(v >> 23) & 255], 1);
                }
                __syncthreads();
                int v = sh1[t];
                for (int o = 1; o < 256; o <<= 1) {
                    int x = (t >= o) ? sh1[t - o] : 0;
                    __syncthreads();
                    sh1[t] += x;
                    __syncthreads();
                }
                const int excl = sh1[t] - v;
                const int idx = bb * 256 + t;
                if (idx <= N) rowptr[idx] = brow + excl;   // covers rowptr[N]=E
                sh3[t] = excl;
                __syncthreads();
                for (int i = t; i < n; i += 256) {
                    unsigned int e = eb[i];
                    int slot = atomicAdd(&sh3[(e >> 23) & 255], 1);
                    sedge[brow + slot] = ((e & 0xFFFFu) << 8)
                                       | (((e >> 16) & 0x7Fu) << 25);
                }
                __syncthreads();
            }
        }
        if (ph < phi) cooperative_groups::this_grid().sync();
    }
}

// One wave per dst: gather h_bf[src] (256B, 1 dword/lane), accumulate 4 basis
// float2 pairs/lane (v_pk_fma_f32), scale by norm, store bf16 A-panel row.
// Round-7 measured: 46.0 us, 2.93 TB/s, occ 61% (unroll-16, VGPR 32).
__global__ __launch_bounds__(256, 8) void aggregate_pre(
    const unsigned short* __restrict__ hbf,
    const int* __restrict__ rowptr,
    const unsigned int* __restrict__ sedge,
    const float* __restrict__ coeff,
    const float* __restrict__ norm,
    unsigned short* __restrict__ A2, int N, int R)
{
    __shared__ float scoef[512];               // R*4 <= 512
    for (int i = threadIdx.x; i < R * 4; i += 256) scoef[i] = coeff[i];
    __syncthreads();

    const int wave = threadIdx.x >> 6;
    const int lane = threadIdx.x & 63;
    const int d = blockIdx.x * 4 + wave;
    if (d >= N) return;
    int i = rowptr[d];
    const int end = rowptr[d + 1];

    const char* hbase = (const char*)hbf + lane * 4;

    floatx2 a0 = {0.f, 0.f}, a1 = {0.f, 0.f}, a2 = {0.f, 0.f}, a3 = {0.f, 0.f};

#define EDGE_LOAD(v, u) \
    unsigned int u = *(const unsigned int*)(hbase + ((v) & 0x00FFFF00u));
#define EDGE_MATH(v, u) { \
    const float4 c = *(const float4*)((const char*)scoef + (((v) >> 25) << 4)); \
    floatx2 hp; \
    hp[0] = __uint_as_float((u) << 16); \
    hp[1] = __uint_as_float((u) & 0xFFFF0000u); \
    a0 = __builtin_elementwise_fma((floatx2){c.x, c.x}, hp, a0); \
    a1 = __builtin_elementwise_fma((floatx2){c.y, c.y}, hp, a1); \
    a2 = __builtin_elementwise_fma((floatx2){c.z, c.z}, hp, a2); \
    a3 = __builtin_elementwise_fma((floatx2){c.w, c.w}, hp, a3); }

    while (i < end && (i & 3)) {
        unsigned int v = sedge[i];
        EDGE_LOAD(v, u)
        EDGE_MATH(v, u)
        ++i;
    }
    for (; i + 16 <= end; i += 16) {
        uint4 e0 = *(const uint4*)(sedge + i);
        uint4 e1 = *(const uint4*)(sedge + i + 4);
        uint4 e2 = *(const uint4*)(sedge + i + 8);
        uint4 e3 = *(const uint4*)(sedge + i + 12);
        EDGE_LOAD(e0.x, u0)  EDGE_LOAD(e0.y, u1)  EDGE_LOAD(e0.z, u2)  EDGE_LOAD(e0.w, u3)
        EDGE_LOAD(e1.x, u4)  EDGE_LOAD(e1.y, u5)  EDGE_LOAD(e1.z, u6)  EDGE_LOAD(e1.w, u7)
        EDGE_LOAD(e2.x, u8)  EDGE_LOAD(e2.y, u9)  EDGE_LOAD(e2.z, u10) EDGE_LOAD(e2.w, u11)
        EDGE_LOAD(e3.x, u12) EDGE_LOAD(e3.y, u13) EDGE_LOAD(e3.z, u14) EDGE_LOAD(e3.w, u15)
        EDGE_MATH(e0.x, u0)  EDGE_MATH(e0.y, u1)  EDGE_MATH(e0.z, u2)  EDGE_MATH(e0.w, u3)
        EDGE_MATH(e1.x, u4)  EDGE_MATH(e1.y, u5)  EDGE_MATH(e1.z, u6)  EDGE_MATH(e1.w, u7)
        EDGE_MATH(e2.x, u8)  EDGE_MATH(e2.y, u9)  EDGE_MATH(e2.z, u10) EDGE_MATH(e2.w, u11)
        EDGE_MATH(e3.x, u12) EDGE_MATH(e3.y, u13) EDGE_MATH(e3.z, u14) EDGE_MATH(e3.w, u15)
    }
    for (; i + 8 <= end; i += 8) {
        uint4 e0 = *(const uint4*)(sedge + i);
        uint4 e1 = *(const uint4*)(sedge + i + 4);
        EDGE_LOAD(e0.x, u0) EDGE_LOAD(e0.y, u1) EDGE_LOAD(e0.z, u2) EDGE_LOAD(e0.w, u3)
        EDGE_LOAD(e1.x, u4) EDGE_LOAD(e1.y, u5) EDGE_LOAD(e1.z, u6) EDGE_LOAD(e1.w, u7)
        EDGE_MATH(e0.x, u0) EDGE_MATH(e0.y, u1) EDGE_MATH(e0.z, u2) EDGE_MATH(e0.w, u3)
        EDGE_MATH(e1.x, u4) EDGE_MATH(e1.y, u5) EDGE_MATH(e1.z, u6) EDGE_MATH(e1.w, u7)
    }
    for (; i + 4 <= end; i += 4) {
        uint4 e0 = *(const uint4*)(sedge + i);
        EDGE_LOAD(e0.x, u0) EDGE_LOAD(e0.y, u1) EDGE_LOAD(e0.z, u2) EDGE_LOAD(e0.w, u3)
        EDGE_MATH(e0.x, u0) EDGE_MATH(e0.y, u1) EDGE_MATH(e0.z, u2) EDGE_MATH(e0.w, u3)
    }
    for (; i < end; ++i) {
        unsigned int v = sedge[i];
        EDGE_LOAD(v, u)
        EDGE_MATH(v, u)
    }
#undef EDGE_LOAD
#undef EDGE_MATH

    const float nm = norm[d];
    unsigned short* row = A2 + (size_t)d * 512 + lane * 2;
    *(unsigned int*)(row)       = (unsigned int)f2bf(a0[0] * nm) | ((unsigned int)f2bf(a0[1] * nm) << 16);
    *(unsigned int*)(row + 128) = (unsigned int)f2bf(a1[0] * nm) | ((unsigned int)f2bf(a1[1] * nm) << 16);
    *(unsigned int*)(row + 256) = (unsigned int)f2bf(a2[0] * nm) | ((unsigned int)f2bf(a2[1] * nm) << 16);
    *(unsigned int*)(row + 384) = (unsigned int)f2bf(a3[0] * nm) | ((unsigned int)f2bf(a3[1] * nm) << 16);
}

// out = relu([A2 | h_bf] @ WT2^T): (N,640)@(640,128), LDS-tiled MFMA GEMM.
__global__ __launch_bounds__(256) void final_gemm(
    const unsigned short* __restrict__ A2,    // (N,512) bf16
    const unsigned short* __restrict__ hbf,   // (N,128) bf16
    const unsigned short* __restrict__ WT2,   // (128,640) bf16 [col][k]
    float* __restrict__ out, int N)
{
    __shared__ char sA[16384];   // [kc 0..7][row 0..127] x 16B
    __shared__ char sB[16384];   // [kc 0..7][col 0..127] x 16B
    const int t = threadIdx.x;
    const int w = t >> 6;
    const int lane = t & 63;
    const int quad = lane >> 4;
    const int low  = lane & 15;
    const int wr = w >> 1, wc = w & 1;   // 2x2 wave grid of 64x64 sub-tiles
    const int m0 = blockIdx.x * 128;

    floatx4 acc[4][4];
#pragma unroll
    for (int mt = 0; mt < 4; ++mt)
#pragma unroll
        for (int nt = 0; nt < 4; ++nt) acc[mt][nt] = (floatx4){0.f, 0.f, 0.f, 0.f};

    for (int it = 0; it < 10; ++it) {
        const int k0 = it * 64;
#pragma unroll
        for (int i = 0; i < 4; ++i) {
            const int slot = i * 256 + t;          // 0..1023
            const int kc  = slot >> 7;             // 0..7
            const int idx = slot & 127;            // row / col
            int grow = m0 + idx;
            if (grow >= N) grow = N - 1;           // clamp loads; stores guarded
            const unsigned short* gA = (k0 < 512)
                ? A2  + (size_t)grow * 512 + k0 + kc * 8
                : hbf + (size_t)grow * 128 + (k0 - 512) + kc * 8;
            const unsigned short* gB = WT2 + (size_t)idx * 640 + k0 + kc * 8;
            stage16(gA, sA + (size_t)(i * 256 + w * 64) * 16, lane);
            stage16(gB, sB + (size_t)(i * 256 + w * 64) * 16, lane);
        }
        __syncthreads();

#pragma unroll
        for (int ks = 0; ks < 2; ++ks) {
            bf16x8 af[4], bfr[4];
#pragma unroll
            for (int mt = 0; mt < 4; ++mt)
                af[mt] = *(const bf16x8*)(sA + (size_t)(((ks * 4 + quad) << 7) + wr * 64 + mt * 16 + low) * 16);
#pragma unroll
            for (int nt = 0; nt < 4; ++nt)
                bfr[nt] = *(const bf16x8*)(sB + (size_t)(((ks * 4 + quad) << 7) + wc * 64 + nt * 16 + low) * 16);
#pragma unroll
            for (int mt = 0; mt < 4; ++mt)
#pragma unroll
                for (int nt = 0; nt < 4; ++nt)
                    acc[mt][nt] = __builtin_amdgcn_mfma_f32_16x16x32_bf16(af[mt], bfr[nt], acc[mt][nt], 0, 0, 0);
        }
        __syncthreads();
    }

    // C/D: col=lane&15, row=(lane>>4)*4+reg
#pragma unroll
    for (int mt = 0; mt < 4; ++mt) {
#pragma unroll
        for (int nt = 0; nt < 4; ++nt) {
            const int c = wc * 64 + nt * 16 + low;
#pragma unroll
            for (int r = 0; r < 4; ++r) {
                int rr = m0 + wr * 64 + mt * 16 + quad * 4 + r;
                if (rr < N) out[(size_t)rr * 128 + c] = fmaxf(acc[mt][nt][r], 0.f);
            }
        }
    }
}

extern "C" void kernel_launch(void* const* d_in, const int* in_sizes, int n_in,
                              void* d_out, int out_size, void* d_ws, size_t ws_size,
                              hipStream_t stream)
{
    const float* h     = (const float*)d_in[0];
    const float* norm  = (const float*)d_in[1];
    const int*   src   = (const int*)d_in[2];
    const int*   dst   = (const int*)d_in[3];
    const int*   rel   = (const int*)d_in[4];
    const float* basis = (const float*)d_in[5];
    const float* coeff = (const float*)d_in[6];
    const float* loopw = (const float*)d_in[7];
    float* out = (float*)d_out;

    const int N = in_sizes[1];       // 50000
    const int E = in_sizes[2];       // 800000
    const int R = in_sizes[6] / 4;   // 100

    const int nB    = (N + 255) >> 8;              // 196 coarse buckets
    const int nblkH = (E + EPB - 1) / EPB;         // 196 edge chunks
    const int M     = nB * nblkH;                  // 38416 scan elements
    const int NBs   = (M + 255) / 256;             // 151 scan blocks (<=256)

    char* ws = (char*)d_ws;
    size_t off = 0;
    auto walloc = [&](size_t bytes) -> char* {
        char* p = ws + off;
        off = (off + bytes + 255) & ~(size_t)255;
        return p;
    };
    unsigned short* A2     = (unsigned short*)walloc((size_t)N * 512 * 2);  // 51.2 MB
    unsigned short* hbf    = (unsigned short*)walloc((size_t)N * 128 * 2);  // 12.8 MB
    unsigned short* WT2    = (unsigned short*)walloc(128 * 640 * 2);
    int*            rowptr = (int*)walloc((size_t)(N + 1) * 4);
    int*            bsum   = (int*)walloc((size_t)NBs * 4);
    int*            gh     = (int*)walloc((size_t)M * 4);
    int*            sgh    = (int*)walloc((size_t)M * 4);
    unsigned int*   tmp    = (unsigned int*)walloc((size_t)E * 4);
    unsigned int*   sedge  = (unsigned int*)walloc((size_t)E * 4);

    int nconv8 = N * 16;                           // 8 floats per thread

    // Co-residency limit for the coop launch (host-only queries: capture-safe).
    static int coop_max = -1;
    if (coop_max < 0) {
        int perCU = 0, nCU = 0, dev = 0;
        if (hipGetDevice(&dev) != hipSuccess) dev = 0;
        if (hipOccupancyMaxActiveBlocksPerMultiprocessor(
                &perCU, (const void*)prefix_pipe, 256, 0) != hipSuccess) perCU = 0;
        if (hipDeviceGetAttribute(&nCU, hipDeviceAttributeMultiprocessorCount,
                                  dev) != hipSuccess) nCU = 0;
        coop_max = perCU * nCU;
    }

    bool done = false;
    if (coop_max >= 256) {                         // need a real full-machine grid
        int G = coop_max < 2048 ? coop_max : 2048;
        int plo = 0, phi = 4;
        int E_ = E, N_ = N, nB_ = nB, nblkH_ = nblkH, M_ = M, NBs_ = NBs;
        void* args[] = {
            (void*)&h, (void*)&hbf, (void*)&nconv8,
            (void*)&dst, (void*)&src, (void*)&rel,
            (void*)&basis, (void*)&loopw, (void*)&WT2,
            (void*)&gh, (void*)&bsum, (void*)&sgh,
            (void*)&tmp, (void*)&sedge, (void*)&rowptr,
            (void*)&E_, (void*)&N_, (void*)&nB_, (void*)&nblkH_,
            (void*)&M_, (void*)&NBs_, (void*)&plo, (void*)&phi
        };
        done = hipLaunchCooperativeKernel((void*)prefix_pipe, dim3(G), dim3(256),
                                          args, 0, stream) == hipSuccess;
    }
    if (!done) {
        // Per-phase normal launches (plo==phi -> grid sync never executed)
        const int nb_conv = (nconv8 + 255) / 256;  // 3125: full machine for ph0
        for (int ph = 0; ph <= 4; ++ph) {
            int g = (ph == 0) ? nb_conv : (ph <= 2 ? NBs : (ph == 3 ? nblkH : nB));
            prefix_pipe<<<g, 256, 0, stream>>>(h, hbf, nconv8, dst, src, rel,
                                               basis, loopw, WT2, gh, bsum, sgh,
                                               tmp, sedge, rowptr,
                                               E, N, nB, nblkH, M, NBs, ph, ph);
        }
    }
    aggregate_pre<<<(N + 3) / 4, 256, 0, stream>>>(hbf, rowptr, sedge, coeff, norm, A2, N, R);
    final_gemm<<<(N + 127) / 128, 256, 0, stream>>>(A2, hbf, WT2, out, N);
}

// Round 9
// 189.858 us; speedup vs baseline: 3.5301x; 3.5301x over previous
//
#include <hip/hip_runtime.h>

typedef short bf16x8 __attribute__((ext_vector_type(8)));
typedef float floatx4 __attribute__((ext_vector_type(4)));
typedef float floatx2 __attribute__((ext_vector_type(2)));

typedef const __attribute__((address_space(1))) void* gas_ptr;
typedef __attribute__((address_space(3))) void* las_ptr;

#define EPB  4096   // edges per hist/scatter chunk
#define MAXB 6144   // bucket capacity (mean 4096, sigma 64 -> 32 sigma headroom)

__device__ __forceinline__ unsigned short f2bf(float f) {
    unsigned int u = __float_as_uint(f);
    unsigned int r = u + 0x7fffu + ((u >> 16) & 1u);   // RNE
    return (unsigned short)(r >> 16);
}

// Async global->LDS 16B: HW writes lbase + lane*16; g is the per-lane source.
__device__ __forceinline__ void stage16(const void* g, void* lbase, int lane) {
#if __has_builtin(__builtin_amdgcn_global_load_lds)
    __builtin_amdgcn_global_load_lds((gas_ptr)g, (las_ptr)lbase, 16, 0, 0);
#else
    *(float4*)((char*)lbase + lane * 16) = *(const float4*)g;
#endif
}

// Fused prep, 1024-thread blocks (r9: the 196-block phases were <1 block/CU
// with 4 waves -- widened to 16 waves/block for latency hiding).
// blocks [0,nb_conv): h->bf16, 8 floats/thread; next nblkH: per-chunk
// coarse-bucket (dst>>8) LDS histogram -> gh[bin][chunk] (NO global atomics);
// last 128: weight transpose WT2[c][k].
__global__ __launch_bounds__(1024) void prep_all(
    const float* __restrict__ h, unsigned short* __restrict__ hbf, int nconv8,
    const int* __restrict__ dst, int* __restrict__ gh, int E, int nB, int nblkH,
    const float* __restrict__ basis, const float* __restrict__ loopw,
    unsigned short* __restrict__ WT2, int nb_conv)
{
    __shared__ int lh[256];
    const int b = blockIdx.x;
    const int t = threadIdx.x;
    if (b < nb_conv) {
        int idx = b * 1024 + t;                // one thread = 8 floats -> 8 bf16
        if (idx < nconv8) {
            const float4 v0 = *(const float4*)(h + (size_t)idx * 8);
            const float4 v1 = *(const float4*)(h + (size_t)idx * 8 + 4);
            uint4 p;
            p.x = (unsigned int)f2bf(v0.x) | ((unsigned int)f2bf(v0.y) << 16);
            p.y = (unsigned int)f2bf(v0.z) | ((unsigned int)f2bf(v0.w) << 16);
            p.z = (unsigned int)f2bf(v1.x) | ((unsigned int)f2bf(v1.y) << 16);
            p.w = (unsigned int)f2bf(v1.z) | ((unsigned int)f2bf(v1.w) << 16);
            *(uint4*)(hbf + (size_t)idx * 8) = p;
        }
    } else if (b < nb_conv + nblkH) {
        const int blk = b - nb_conv;
        if (t < 256) lh[t] = 0;
        __syncthreads();
        const int cbase = blk * EPB;
#pragma unroll
        for (int j = 0; j < EPB / 1024; ++j) {
            int e = cbase + j * 1024 + t;
            if (e < E) atomicAdd(&lh[dst[e] >> 8], 1);
        }
        __syncthreads();
        if (t < nB) gh[(size_t)t * nblkH + blk] = lh[t];
    } else {
        int c = b - nb_conv - nblkH;            // 0..127
        if (t < 640) {
            float v;
            if (t < 512) v = basis[(size_t)t * 128 + c];
            else         v = loopw[(size_t)(t - 512) * 128 + c];
            WT2[(size_t)c * 640 + t] = f2bf(v);
        }
    }
}

// Generic 2-kernel exclusive scan over M ints (M <= 256*256).
__global__ __launch_bounds__(256) void scan1(
    const int* __restrict__ in, int* __restrict__ bsum, int M)
{
    __shared__ int s[256];
    int i = blockIdx.x * 256 + threadIdx.x;
    int t = threadIdx.x;
    s[t] = (i < M) ? in[i] : 0;
    __syncthreads();
    for (int o = 128; o > 0; o >>= 1) {
        if (t < o) s[t] += s[t + o];
        __syncthreads();
    }
    if (t == 0) bsum[blockIdx.x] = s[0];
}

__global__ __launch_bounds__(256) void scan_final(
    const int* __restrict__ in, const int* __restrict__ bsum,
    int* __restrict__ out, int M)
{
    __shared__ int s[256];
    __shared__ int sb[256];
    int t = threadIdx.x;
    int i = blockIdx.x * 256 + t;
    sb[t] = (t < (int)blockIdx.x) ? bsum[t] : 0;
    int v = (i < M) ? in[i] : 0;
    s[t] = v;
    __syncthreads();
    for (int o = 128; o > 0; o >>= 1) {        // reduce sb -> block prefix
        if (t < o) sb[t] += sb[t + o];
        __syncthreads();
    }
    for (int o = 1; o < 256; o <<= 1) {        // inclusive scan of s
        int x = (t >= o) ? s[t - o] : 0;
        __syncthreads();
        s[t] += x;
        __syncthreads();
    }
    if (i < M) out[i] = s[t] - v + sb[0];      // exclusive
}

// Route edges into coarse buckets, 1024-thread blocks (16 waves for latency
// hiding; was 4). Cursors in LDS (seeded from scanned gh); slot assignment
// via LDS atomics; plain stores, sequential within each (bucket,chunk)
// segment. tmp packing: src(16) | rel<<16(7) | (dst&255)<<23(8).
__global__ __launch_bounds__(1024) void scatter_bkt(
    const int* __restrict__ dst, const int* __restrict__ src,
    const int* __restrict__ rel, const int* __restrict__ sgh,
    unsigned int* __restrict__ tmp, int E, int nB, int nblkH)
{
    __shared__ int cur[256];
    const int blk = blockIdx.x;
    const int t = threadIdx.x;
    if (t < nB) cur[t] = sgh[(size_t)t * nblkH + blk];
    __syncthreads();
    const int cbase = blk * EPB;
#pragma unroll
    for (int j = 0; j < EPB / 1024; ++j) {
        int e = cbase + j * 1024 + t;
        if (e < E) {
            int d = dst[e];
            int slot = atomicAdd(&cur[d >> 8], 1);
            tmp[slot] = (unsigned int)src[e] | ((unsigned int)rel[e] << 16)
                      | ((unsigned int)(d & 255) << 23);
        }
    }
}

// One block per bucket, 1024 threads (16 waves; was 4): finish the sort by
// dst&255 in LDS, emit rowptr for the bucket's 256 dsts and the dst-sorted
// packed edges (src<<8 | rel<<25). The 256-bin scan runs on threads 0..255
// with block-uniform barriers.
__global__ __launch_bounds__(1024) void bucket_sort(
    const unsigned int* __restrict__ tmp, const int* __restrict__ sgh,
    unsigned int* __restrict__ sedge, int* __restrict__ rowptr,
    int E, int N, int nB, int nblkH)
{
    __shared__ unsigned int eb[MAXB];
    __shared__ int hh[256], ss[256], cur[256];
    const int b = blockIdx.x;
    const int t = threadIdx.x;
    const int brow = sgh[(size_t)b * nblkH];
    const int next = (b + 1 < nB) ? sgh[(size_t)(b + 1) * nblkH] : E;
    int n = next - brow;
    if (n > MAXB) n = MAXB;                    // statistically unreachable
    if (t < 256) hh[t] = 0;
    __syncthreads();
    for (int i = t; i < n; i += 1024) {
        unsigned int v = tmp[brow + i];
        eb[i] = v;
        atomicAdd(&hh[(v >> 23) & 255], 1);
    }
    __syncthreads();
    int v = 0;
    if (t < 256) { v = hh[t]; ss[t] = v; }
    __syncthreads();
    for (int o = 1; o < 256; o <<= 1) {
        int x = 0;
        if (t < 256 && t >= o) x = ss[t - o];
        __syncthreads();
        if (t < 256) ss[t] += x;
        __syncthreads();
    }
    if (t < 256) {
        const int excl = ss[t] - v;
        const int idx = b * 256 + t;
        if (idx <= N) rowptr[idx] = brow + excl;   // covers rowptr[N]=E too
        cur[t] = excl;
    }
    __syncthreads();
    for (int i = t; i < n; i += 1024) {
        unsigned int e = eb[i];
        int slot = atomicAdd(&cur[(e >> 23) & 255], 1);
        sedge[brow + slot] = ((e & 0xFFFFu) << 8) | (((e >> 16) & 0x7Fu) << 25);
    }
}

// One wave per dst: gather h_bf[src] (256B, 1 dword/lane), accumulate 4 basis
// float2 pairs/lane (v_pk_fma_f32), scale by norm, store bf16 A-panel row.
// Round-7 measured: 46.0 us, 2.93 TB/s, occ 61% (unroll-16, VGPR 32).
__global__ __launch_bounds__(256, 8) void aggregate_pre(
    const unsigned short* __restrict__ hbf,
    const int* __restrict__ rowptr,
    const unsigned int* __restrict__ sedge,
    const float* __restrict__ coeff,
    const float* __restrict__ norm,
    unsigned short* __restrict__ A2, int N, int R)
{
    __shared__ float scoef[512];               // R*4 <= 512
    for (int i = threadIdx.x; i < R * 4; i += 256) scoef[i] = coeff[i];
    __syncthreads();

    const int wave = threadIdx.x >> 6;
    const int lane = threadIdx.x & 63;
    const int d = blockIdx.x * 4 + wave;
    if (d >= N) return;
    int i = rowptr[d];
    const int end = rowptr[d + 1];

    const char* hbase = (const char*)hbf + lane * 4;

    floatx2 a0 = {0.f, 0.f}, a1 = {0.f, 0.f}, a2 = {0.f, 0.f}, a3 = {0.f, 0.f};

#define EDGE_LOAD(v, u) \
    unsigned int u = *(const unsigned int*)(hbase + ((v) & 0x00FFFF00u));
#define EDGE_MATH(v, u) { \
    const float4 c = *(const float4*)((const char*)scoef + (((v) >> 25) << 4)); \
    floatx2 hp; \
    hp[0] = __uint_as_float((u) << 16); \
    hp[1] = __uint_as_float((u) & 0xFFFF0000u); \
    a0 = __builtin_elementwise_fma((floatx2){c.x, c.x}, hp, a0); \
    a1 = __builtin_elementwise_fma((floatx2){c.y, c.y}, hp, a1); \
    a2 = __builtin_elementwise_fma((floatx2){c.z, c.z}, hp, a2); \
    a3 = __builtin_elementwise_fma((floatx2){c.w, c.w}, hp, a3); }

    while (i < end && (i & 3)) {
        unsigned int v = sedge[i];
        EDGE_LOAD(v, u)
        EDGE_MATH(v, u)
        ++i;
    }
    for (; i + 16 <= end; i += 16) {
        uint4 e0 = *(const uint4*)(sedge + i);
        uint4 e1 = *(const uint4*)(sedge + i + 4);
        uint4 e2 = *(const uint4*)(sedge + i + 8);
        uint4 e3 = *(const uint4*)(sedge + i + 12);
        EDGE_LOAD(e0.x, u0)  EDGE_LOAD(e0.y, u1)  EDGE_LOAD(e0.z, u2)  EDGE_LOAD(e0.w, u3)
        EDGE_LOAD(e1.x, u4)  EDGE_LOAD(e1.y, u5)  EDGE_LOAD(e1.z, u6)  EDGE_LOAD(e1.w, u7)
        EDGE_LOAD(e2.x, u8)  EDGE_LOAD(e2.y, u9)  EDGE_LOAD(e2.z, u10) EDGE_LOAD(e2.w, u11)
        EDGE_LOAD(e3.x, u12) EDGE_LOAD(e3.y, u13) EDGE_LOAD(e3.z, u14) EDGE_LOAD(e3.w, u15)
        EDGE_MATH(e0.x, u0)  EDGE_MATH(e0.y, u1)  EDGE_MATH(e0.z, u2)  EDGE_MATH(e0.w, u3)
        EDGE_MATH(e1.x, u4)  EDGE_MATH(e1.y, u5)  EDGE_MATH(e1.z, u6)  EDGE_MATH(e1.w, u7)
        EDGE_MATH(e2.x, u8)  EDGE_MATH(e2.y, u9)  EDGE_MATH(e2.z, u10) EDGE_MATH(e2.w, u11)
        EDGE_MATH(e3.x, u12) EDGE_MATH(e3.y, u13) EDGE_MATH(e3.z, u14) EDGE_MATH(e3.w, u15)
    }
    for (; i + 8 <= end; i += 8) {
        uint4 e0 = *(const uint4*)(sedge + i);
        uint4 e1 = *(const uint4*)(sedge + i + 4);
        EDGE_LOAD(e0.x, u0) EDGE_LOAD(e0.y, u1) EDGE_LOAD(e0.z, u2) EDGE_LOAD(e0.w, u3)
        EDGE_LOAD(e1.x, u4) EDGE_LOAD(e1.y, u5) EDGE_LOAD(e1.z, u6) EDGE_LOAD(e1.w, u7)
        EDGE_MATH(e0.x, u0) EDGE_MATH(e0.y, u1) EDGE_MATH(e0.z, u2) EDGE_MATH(e0.w, u3)
        EDGE_MATH(e1.x, u4) EDGE_MATH(e1.y, u5) EDGE_MATH(e1.z, u6) EDGE_MATH(e1.w, u7)
    }
    for (; i + 4 <= end; i += 4) {
        uint4 e0 = *(const uint4*)(sedge + i);
        EDGE_LOAD(e0.x, u0) EDGE_LOAD(e0.y, u1) EDGE_LOAD(e0.z, u2) EDGE_LOAD(e0.w, u3)
        EDGE_MATH(e0.x, u0) EDGE_MATH(e0.y, u1) EDGE_MATH(e0.z, u2) EDGE_MATH(e0.w, u3)
    }
    for (; i < end; ++i) {
        unsigned int v = sedge[i];
        EDGE_LOAD(v, u)
        EDGE_MATH(v, u)
    }
#undef EDGE_LOAD
#undef EDGE_MATH

    const float nm = norm[d];
    unsigned short* row = A2 + (size_t)d * 512 + lane * 2;
    *(unsigned int*)(row)       = (unsigned int)f2bf(a0[0] * nm) | ((unsigned int)f2bf(a0[1] * nm) << 16);
    *(unsigned int*)(row + 128) = (unsigned int)f2bf(a1[0] * nm) | ((unsigned int)f2bf(a1[1] * nm) << 16);
    *(unsigned int*)(row + 256) = (unsigned int)f2bf(a2[0] * nm) | ((unsigned int)f2bf(a2[1] * nm) << 16);
    *(unsigned int*)(row + 384) = (unsigned int)f2bf(a3[0] * nm) | ((unsigned int)f2bf(a3[1] * nm) << 16);
}

// out = relu([A2 | h_bf] @ WT2^T): (N,640)@(640,128), LDS-tiled MFMA GEMM.
__global__ __launch_bounds__(256) void final_gemm(
    const unsigned short* __restrict__ A2,    // (N,512) bf16
    const unsigned short* __restrict__ hbf,   // (N,128) bf16
    const unsigned short* __restrict__ WT2,   // (128,640) bf16 [col][k]
    float* __restrict__ out, int N)
{
    __shared__ char sA[16384];   // [kc 0..7][row 0..127] x 16B
    __shared__ char sB[16384];   // [kc 0..7][col 0..127] x 16B
    const int t = threadIdx.x;
    const int w = t >> 6;
    const int lane = t & 63;
    const int quad = lane >> 4;
    const int low  = lane & 15;
    const int wr = w >> 1, wc = w & 1;   // 2x2 wave grid of 64x64 sub-tiles
    const int m0 = blockIdx.x * 128;

    floatx4 acc[4][4];
#pragma unroll
    for (int mt = 0; mt < 4; ++mt)
#pragma unroll
        for (int nt = 0; nt < 4; ++nt) acc[mt][nt] = (floatx4){0.f, 0.f, 0.f, 0.f};

    for (int it = 0; it < 10; ++it) {
        const int k0 = it * 64;
#pragma unroll
        for (int i = 0; i < 4; ++i) {
            const int slot = i * 256 + t;          // 0..1023
            const int kc  = slot >> 7;             // 0..7
            const int idx = slot & 127;            // row / col
            int grow = m0 + idx;
            if (grow >= N) grow = N - 1;           // clamp loads; stores guarded
            const unsigned short* gA = (k0 < 512)
                ? A2  + (size_t)grow * 512 + k0 + kc * 8
                : hbf + (size_t)grow * 128 + (k0 - 512) + kc * 8;
            const unsigned short* gB = WT2 + (size_t)idx * 640 + k0 + kc * 8;
            stage16(gA, sA + (size_t)(i * 256 + w * 64) * 16, lane);
            stage16(gB, sB + (size_t)(i * 256 + w * 64) * 16, lane);
        }
        __syncthreads();

#pragma unroll
        for (int ks = 0; ks < 2; ++ks) {
            bf16x8 af[4], bfr[4];
#pragma unroll
            for (int mt = 0; mt < 4; ++mt)
                af[mt] = *(const bf16x8*)(sA + (size_t)(((ks * 4 + quad) << 7) + wr * 64 + mt * 16 + low) * 16);
#pragma unroll
            for (int nt = 0; nt < 4; ++nt)
                bfr[nt] = *(const bf16x8*)(sB + (size_t)(((ks * 4 + quad) << 7) + wc * 64 + nt * 16 + low) * 16);
#pragma unroll
            for (int mt = 0; mt < 4; ++mt)
#pragma unroll
                for (int nt = 0; nt < 4; ++nt)
                    acc[mt][nt] = __builtin_amdgcn_mfma_f32_16x16x32_bf16(af[mt], bfr[nt], acc[mt][nt], 0, 0, 0);
        }
        __syncthreads();
    }

    // C/D: col=lane&15, row=(lane>>4)*4+reg
#pragma unroll
    for (int mt = 0; mt < 4; ++mt) {
#pragma unroll
        for (int nt = 0; nt < 4; ++nt) {
            const int c = wc * 64 + nt * 16 + low;
#pragma unroll
            for (int r = 0; r < 4; ++r) {
                int rr = m0 + wr * 64 + mt * 16 + quad * 4 + r;
                if (rr < N) out[(size_t)rr * 128 + c] = fmaxf(acc[mt][nt][r], 0.f);
            }
        }
    }
}

extern "C" void kernel_launch(void* const* d_in, const int* in_sizes, int n_in,
                              void* d_out, int out_size, void* d_ws, size_t ws_size,
                              hipStream_t stream)
{
    const float* h     = (const float*)d_in[0];
    const float* norm  = (const float*)d_in[1];
    const int*   src   = (const int*)d_in[2];
    const int*   dst   = (const int*)d_in[3];
    const int*   rel   = (const int*)d_in[4];
    const float* basis = (const float*)d_in[5];
    const float* coeff = (const float*)d_in[6];
    const float* loopw = (const float*)d_in[7];
    float* out = (float*)d_out;

    const int N = in_sizes[1];       // 50000
    const int E = in_sizes[2];       // 800000
    const int R = in_sizes[6] / 4;   // 100

    const int nB    = (N + 255) >> 8;              // 196 coarse buckets
    const int nblkH = (E + EPB - 1) / EPB;         // 196 edge chunks
    const int M     = nB * nblkH;                  // 38416 scan elements
    const int NBs   = (M + 255) / 256;             // 151 scan blocks (<=256)

    char* ws = (char*)d_ws;
    size_t off = 0;
    auto walloc = [&](size_t bytes) -> char* {
        char* p = ws + off;
        off = (off + bytes + 255) & ~(size_t)255;
        return p;
    };
    unsigned short* A2     = (unsigned short*)walloc((size_t)N * 512 * 2);  // 51.2 MB
    unsigned short* hbf    = (unsigned short*)walloc((size_t)N * 128 * 2);  // 12.8 MB
    unsigned short* WT2    = (unsigned short*)walloc(128 * 640 * 2);
    int*            rowptr = (int*)walloc((size_t)(N + 1) * 4);
    int*            bsum   = (int*)walloc((size_t)NBs * 4);
    int*            gh     = (int*)walloc((size_t)M * 4);
    int*            sgh    = (int*)walloc((size_t)M * 4);
    unsigned int*   tmp    = (unsigned int*)walloc((size_t)E * 4);
    unsigned int*   sedge  = (unsigned int*)walloc((size_t)E * 4);

    const int nconv8  = N * 16;                    // 8 floats per thread
    const int nb_conv = (nconv8 + 1023) / 1024;    // 782

    prep_all<<<nb_conv + nblkH + 128, 1024, 0, stream>>>(
        h, hbf, nconv8, dst, gh, E, nB, nblkH, basis, loopw, WT2, nb_conv);
    scan1<<<NBs, 256, 0, stream>>>(gh, bsum, M);
    scan_final<<<NBs, 256, 0, stream>>>(gh, bsum, sgh, M);
    scatter_bkt<<<nblkH, 1024, 0, stream>>>(dst, src, rel, sgh, tmp, E, nB, nblkH);
    bucket_sort<<<nB, 1024, 0, stream>>>(tmp, sgh, sedge, rowptr, E, N, nB, nblkH);
    aggregate_pre<<<(N + 3) / 4, 256, 0, stream>>>(hbf, rowptr, sedge, coeff, norm, A2, N, R);
    final_gemm<<<(N + 127) / 128, 256, 0, stream>>>(A2, hbf, WT2, out, N);
}

// Round 10
// 187.394 us; speedup vs baseline: 3.5765x; 1.0131x over previous
//
#include <hip/hip_runtime.h>

typedef short bf16x8 __attribute__((ext_vector_type(8)));
typedef float floatx4 __attribute__((ext_vector_type(4)));
typedef float floatx2 __attribute__((ext_vector_type(2)));

typedef const __attribute__((address_space(1))) void* gas_ptr;
typedef __attribute__((address_space(3))) void* las_ptr;

#define EPB  4096   // edges per hist/scatter chunk
#define MAXB 6144   // bucket capacity (mean 4081, sigma ~64 -> +32 sigma)

__device__ __forceinline__ unsigned short f2bf(float f) {
    unsigned int u = __float_as_uint(f);
    unsigned int r = u + 0x7fffu + ((u >> 16) & 1u);   // RNE
    return (unsigned short)(r >> 16);
}

// Async global->LDS 16B: HW writes lbase + lane*16; g is the per-lane source.
__device__ __forceinline__ void stage16(const void* g, void* lbase, int lane) {
#if __has_builtin(__builtin_amdgcn_global_load_lds)
    __builtin_amdgcn_global_load_lds((gas_ptr)g, (las_ptr)lbase, 16, 0, 0);
#else
    *(float4*)((char*)lbase + lane * 16) = *(const float4*)g;
#endif
}

// R10 restructure: tmp is [bucket][MAXB] FIXED-CAPACITY -> the global exclusive
// scan (2 kernels) disappears, and hist+claim+scatter fuse into prep_all:
// each chunk-block LDS-histograms its 4096 edges, claims a contiguous range
// per bin with ONE global atomicAdd per (block,bin) (38k atomics on 196 hot
// 64B-padded counters -- unlike r3's 50k-counter disaster, these lines stay
// resident), then scatters through LDS cursors. Pipeline: 7 -> 4 kernels
// (launch overhead ~8us each was ~40% of the prefix cost).
//
// prep_all (1024 thr): blocks [0,nb_conv) h->bf16 8 floats/thread;
// next nblkH: hist+claim+scatter (tmp packing: src | rel<<16 | (dst&255)<<23);
// last 128: weight transpose WT2[c][k].
__global__ __launch_bounds__(1024) void prep_all(
    const float* __restrict__ h, unsigned short* __restrict__ hbf, int nconv8,
    const int* __restrict__ dst, const int* __restrict__ src,
    const int* __restrict__ rel, int* __restrict__ bcnt,
    unsigned int* __restrict__ tmp, int E, int nB, int nblkH,
    const float* __restrict__ basis, const float* __restrict__ loopw,
    unsigned short* __restrict__ WT2, int nb_conv)
{
    __shared__ int lh[256], cur[256];
    const int b = blockIdx.x;
    const int t = threadIdx.x;
    if (b < nb_conv) {
        int idx = b * 1024 + t;                // one thread = 8 floats -> 8 bf16
        if (idx < nconv8) {
            const float4 v0 = *(const float4*)(h + (size_t)idx * 8);
            const float4 v1 = *(const float4*)(h + (size_t)idx * 8 + 4);
            uint4 p;
            p.x = (unsigned int)f2bf(v0.x) | ((unsigned int)f2bf(v0.y) << 16);
            p.y = (unsigned int)f2bf(v0.z) | ((unsigned int)f2bf(v0.w) << 16);
            p.z = (unsigned int)f2bf(v1.x) | ((unsigned int)f2bf(v1.y) << 16);
            p.w = (unsigned int)f2bf(v1.z) | ((unsigned int)f2bf(v1.w) << 16);
            *(uint4*)(hbf + (size_t)idx * 8) = p;
        }
    } else if (b < nb_conv + nblkH) {
        const int blk = b - nb_conv;
        if (t < 256) lh[t] = 0;
        __syncthreads();
        const int cbase = blk * EPB;
        int dd[EPB / 1024];
#pragma unroll
        for (int j = 0; j < EPB / 1024; ++j) {
            int e = cbase + j * 1024 + t;
            dd[j] = (e < E) ? dst[e] : -1;
            if (dd[j] >= 0) atomicAdd(&lh[dd[j] >> 8], 1);
        }
        __syncthreads();
        if (t < 256) {
            int c = lh[t];
            int base = c ? atomicAdd(&bcnt[t * 16], c) : 0;
            cur[t] = t * MAXB + base;          // bucket-region absolute cursor
        }
        __syncthreads();
#pragma unroll
        for (int j = 0; j < EPB / 1024; ++j) {
            int e = cbase + j * 1024 + t;
            int d = dd[j];
            if (d >= 0) {
                int bin = d >> 8;
                int slot = atomicAdd(&cur[bin], 1);
                if (slot < (bin + 1) * MAXB)   // capacity guard (unreachable)
                    tmp[slot] = (unsigned int)src[e]
                              | ((unsigned int)rel[e] << 16)
                              | ((unsigned int)(d & 255) << 23);
            }
        }
    } else {
        int c = b - nb_conv - nblkH;            // 0..127
        if (t < 640) {
            float v;
            if (t < 512) v = basis[(size_t)t * 128 + c];
            else         v = loopw[(size_t)(t - 512) * 128 + c];
            WT2[(size_t)c * 640 + t] = f2bf(v);
        }
    }
}

// One block per bucket, 1024 threads: recompute the 196-entry bucket-base scan
// locally from bcnt (784B, L2-hot), then finish the sort by dst&255 in LDS;
// emit rowptr for the bucket's 256 dsts and the dst-sorted compact sedge
// (src<<8 | rel<<25). The 256-wide scans run on threads 0..255 with
// block-uniform barriers.
__global__ __launch_bounds__(1024) void bucket_sort(
    const unsigned int* __restrict__ tmp, const int* __restrict__ bcnt,
    unsigned int* __restrict__ sedge, int* __restrict__ rowptr,
    int E, int N, int nB)
{
    __shared__ unsigned int eb[MAXB];
    __shared__ int hh[256], ss[256], cur[256];
    __shared__ int sbrow, scnt;
    const int b = blockIdx.x;
    const int t = threadIdx.x;

    // bucket bases: exclusive scan of clamped counts
    int c = 0;
    if (t < 256) {
        c = (t < nB) ? bcnt[t * 16] : 0;
        if (c > MAXB) c = MAXB;
        ss[t] = c;
    }
    __syncthreads();
    for (int o = 1; o < 256; o <<= 1) {
        int x = 0;
        if (t < 256 && t >= o) x = ss[t - o];
        __syncthreads();
        if (t < 256) ss[t] += x;
        __syncthreads();
    }
    if (t == b) { sbrow = ss[t] - c; scnt = c; }   // b < nB <= 256
    __syncthreads();
    const int brow = sbrow;
    const int n    = scnt;

    if (t < 256) hh[t] = 0;
    __syncthreads();
    const unsigned int* tb = tmp + (size_t)b * MAXB;
    for (int i = t; i < n; i += 1024) {
        unsigned int v = tb[i];
        eb[i] = v;
        atomicAdd(&hh[(v >> 23) & 255], 1);
    }
    __syncthreads();
    int v = 0;
    if (t < 256) { v = hh[t]; ss[t] = v; }
    __syncthreads();
    for (int o = 1; o < 256; o <<= 1) {
        int x = 0;
        if (t < 256 && t >= o) x = ss[t - o];
        __syncthreads();
        if (t < 256) ss[t] += x;
        __syncthreads();
    }
    if (t < 256) {
        const int excl = ss[t] - v;
        const int idx = b * 256 + t;
        if (idx <= N) rowptr[idx] = brow + excl;   // covers rowptr[N]=E too
        cur[t] = excl;
    }
    __syncthreads();
    for (int i = t; i < n; i += 1024) {
        unsigned int e = eb[i];
        int slot = atomicAdd(&cur[(e >> 23) & 255], 1);
        sedge[brow + slot] = ((e & 0xFFFFu) << 8) | (((e >> 16) & 0x7Fu) << 25);
    }
}

// One wave per dst: gather h_bf[src] (256B, 1 dword/lane), accumulate 4 basis
// float2 pairs/lane (v_pk_fma_f32), scale by norm, store bf16 A-panel row.
// Round-7/9 measured: ~46-47.5 us, 2.83-2.93 TB/s, occ ~64% (unroll-16).
__global__ __launch_bounds__(256, 8) void aggregate_pre(
    const unsigned short* __restrict__ hbf,
    const int* __restrict__ rowptr,
    const unsigned int* __restrict__ sedge,
    const float* __restrict__ coeff,
    const float* __restrict__ norm,
    unsigned short* __restrict__ A2, int N, int R)
{
    __shared__ float scoef[512];               // R*4 <= 512
    for (int i = threadIdx.x; i < R * 4; i += 256) scoef[i] = coeff[i];
    __syncthreads();

    const int wave = threadIdx.x >> 6;
    const int lane = threadIdx.x & 63;
    const int d = blockIdx.x * 4 + wave;
    if (d >= N) return;
    int i = rowptr[d];
    const int end = rowptr[d + 1];

    const char* hbase = (const char*)hbf + lane * 4;

    floatx2 a0 = {0.f, 0.f}, a1 = {0.f, 0.f}, a2 = {0.f, 0.f}, a3 = {0.f, 0.f};

#define EDGE_LOAD(v, u) \
    unsigned int u = *(const unsigned int*)(hbase + ((v) & 0x00FFFF00u));
#define EDGE_MATH(v, u) { \
    const float4 c = *(const float4*)((const char*)scoef + (((v) >> 25) << 4)); \
    floatx2 hp; \
    hp[0] = __uint_as_float((u) << 16); \
    hp[1] = __uint_as_float((u) & 0xFFFF0000u); \
    a0 = __builtin_elementwise_fma((floatx2){c.x, c.x}, hp, a0); \
    a1 = __builtin_elementwise_fma((floatx2){c.y, c.y}, hp, a1); \
    a2 = __builtin_elementwise_fma((floatx2){c.z, c.z}, hp, a2); \
    a3 = __builtin_elementwise_fma((floatx2){c.w, c.w}, hp, a3); }

    while (i < end && (i & 3)) {
        unsigned int v = sedge[i];
        EDGE_LOAD(v, u)
        EDGE_MATH(v, u)
        ++i;
    }
    for (; i + 16 <= end; i += 16) {
        uint4 e0 = *(const uint4*)(sedge + i);
        uint4 e1 = *(const uint4*)(sedge + i + 4);
        uint4 e2 = *(const uint4*)(sedge + i + 8);
        uint4 e3 = *(const uint4*)(sedge + i + 12);
        EDGE_LOAD(e0.x, u0)  EDGE_LOAD(e0.y, u1)  EDGE_LOAD(e0.z, u2)  EDGE_LOAD(e0.w, u3)
        EDGE_LOAD(e1.x, u4)  EDGE_LOAD(e1.y, u5)  EDGE_LOAD(e1.z, u6)  EDGE_LOAD(e1.w, u7)
        EDGE_LOAD(e2.x, u8)  EDGE_LOAD(e2.y, u9)  EDGE_LOAD(e2.z, u10) EDGE_LOAD(e2.w, u11)
        EDGE_LOAD(e3.x, u12) EDGE_LOAD(e3.y, u13) EDGE_LOAD(e3.z, u14) EDGE_LOAD(e3.w, u15)
        EDGE_MATH(e0.x, u0)  EDGE_MATH(e0.y, u1)  EDGE_MATH(e0.z, u2)  EDGE_MATH(e0.w, u3)
        EDGE_MATH(e1.x, u4)  EDGE_MATH(e1.y, u5)  EDGE_MATH(e1.z, u6)  EDGE_MATH(e1.w, u7)
        EDGE_MATH(e2.x, u8)  EDGE_MATH(e2.y, u9)  EDGE_MATH(e2.z, u10) EDGE_MATH(e2.w, u11)
        EDGE_MATH(e3.x, u12) EDGE_MATH(e3.y, u13) EDGE_MATH(e3.z, u14) EDGE_MATH(e3.w, u15)
    }
    for (; i + 8 <= end; i += 8) {
        uint4 e0 = *(const uint4*)(sedge + i);
        uint4 e1 = *(const uint4*)(sedge + i + 4);
        EDGE_LOAD(e0.x, u0) EDGE_LOAD(e0.y, u1) EDGE_LOAD(e0.z, u2) EDGE_LOAD(e0.w, u3)
        EDGE_LOAD(e1.x, u4) EDGE_LOAD(e1.y, u5) EDGE_LOAD(e1.z, u6) EDGE_LOAD(e1.w, u7)
        EDGE_MATH(e0.x, u0) EDGE_MATH(e0.y, u1) EDGE_MATH(e0.z, u2) EDGE_MATH(e0.w, u3)
        EDGE_MATH(e1.x, u4) EDGE_MATH(e1.y, u5) EDGE_MATH(e1.z, u6) EDGE_MATH(e1.w, u7)
    }
    for (; i + 4 <= end; i += 4) {
        uint4 e0 = *(const uint4*)(sedge + i);
        EDGE_LOAD(e0.x, u0) EDGE_LOAD(e0.y, u1) EDGE_LOAD(e0.z, u2) EDGE_LOAD(e0.w, u3)
        EDGE_MATH(e0.x, u0) EDGE_MATH(e0.y, u1) EDGE_MATH(e0.z, u2) EDGE_MATH(e0.w, u3)
    }
    for (; i < end; ++i) {
        unsigned int v = sedge[i];
        EDGE_LOAD(v, u)
        EDGE_MATH(v, u)
    }
#undef EDGE_LOAD
#undef EDGE_MATH

    const float nm = norm[d];
    unsigned short* row = A2 + (size_t)d * 512 + lane * 2;
    *(unsigned int*)(row)       = (unsigned int)f2bf(a0[0] * nm) | ((unsigned int)f2bf(a0[1] * nm) << 16);
    *(unsigned int*)(row + 128) = (unsigned int)f2bf(a1[0] * nm) | ((unsigned int)f2bf(a1[1] * nm) << 16);
    *(unsigned int*)(row + 256) = (unsigned int)f2bf(a2[0] * nm) | ((unsigned int)f2bf(a2[1] * nm) << 16);
    *(unsigned int*)(row + 384) = (unsigned int)f2bf(a3[0] * nm) | ((unsigned int)f2bf(a3[1] * nm) << 16);
}

// out = relu([A2 | h_bf] @ WT2^T): (N,640)@(640,128), LDS-tiled MFMA GEMM.
__global__ __launch_bounds__(256) void final_gemm(
    const unsigned short* __restrict__ A2,    // (N,512) bf16
    const unsigned short* __restrict__ hbf,   // (N,128) bf16
    const unsigned short* __restrict__ WT2,   // (128,640) bf16 [col][k]
    float* __restrict__ out, int N)
{
    __shared__ char sA[16384];   // [kc 0..7][row 0..127] x 16B
    __shared__ char sB[16384];   // [kc 0..7][col 0..127] x 16B
    const int t = threadIdx.x;
    const int w = t >> 6;
    const int lane = t & 63;
    const int quad = lane >> 4;
    const int low  = lane & 15;
    const int wr = w >> 1, wc = w & 1;   // 2x2 wave grid of 64x64 sub-tiles
    const int m0 = blockIdx.x * 128;

    floatx4 acc[4][4];
#pragma unroll
    for (int mt = 0; mt < 4; ++mt)
#pragma unroll
        for (int nt = 0; nt < 4; ++nt) acc[mt][nt] = (floatx4){0.f, 0.f, 0.f, 0.f};

    for (int it = 0; it < 10; ++it) {
        const int k0 = it * 64;
#pragma unroll
        for (int i = 0; i < 4; ++i) {
            const int slot = i * 256 + t;          // 0..1023
            const int kc  = slot >> 7;             // 0..7
            const int idx = slot & 127;            // row / col
            int grow = m0 + idx;
            if (grow >= N) grow = N - 1;           // clamp loads; stores guarded
            const unsigned short* gA = (k0 < 512)
                ? A2  + (size_t)grow * 512 + k0 + kc * 8
                : hbf + (size_t)grow * 128 + (k0 - 512) + kc * 8;
            const unsigned short* gB = WT2 + (size_t)idx * 640 + k0 + kc * 8;
            stage16(gA, sA + (size_t)(i * 256 + w * 64) * 16, lane);
            stage16(gB, sB + (size_t)(i * 256 + w * 64) * 16, lane);
        }
        __syncthreads();

#pragma unroll
        for (int ks = 0; ks < 2; ++ks) {
            bf16x8 af[4], bfr[4];
#pragma unroll
            for (int mt = 0; mt < 4; ++mt)
                af[mt] = *(const bf16x8*)(sA + (size_t)(((ks * 4 + quad) << 7) + wr * 64 + mt * 16 + low) * 16);
#pragma unroll
            for (int nt = 0; nt < 4; ++nt)
                bfr[nt] = *(const bf16x8*)(sB + (size_t)(((ks * 4 + quad) << 7) + wc * 64 + nt * 16 + low) * 16);
#pragma unroll
            for (int mt = 0; mt < 4; ++mt)
#pragma unroll
                for (int nt = 0; nt < 4; ++nt)
                    acc[mt][nt] = __builtin_amdgcn_mfma_f32_16x16x32_bf16(af[mt], bfr[nt], acc[mt][nt], 0, 0, 0);
        }
        __syncthreads();
    }

    // C/D: col=lane&15, row=(lane>>4)*4+reg
#pragma unroll
    for (int mt = 0; mt < 4; ++mt) {
#pragma unroll
        for (int nt = 0; nt < 4; ++nt) {
            const int c = wc * 64 + nt * 16 + low;
#pragma unroll
            for (int r = 0; r < 4; ++r) {
                int rr = m0 + wr * 64 + mt * 16 + quad * 4 + r;
                if (rr < N) out[(size_t)rr * 128 + c] = fmaxf(acc[mt][nt][r], 0.f);
            }
        }
    }
}

extern "C" void kernel_launch(void* const* d_in, const int* in_sizes, int n_in,
                              void* d_out, int out_size, void* d_ws, size_t ws_size,
                              hipStream_t stream)
{
    const float* h     = (const float*)d_in[0];
    const float* norm  = (const float*)d_in[1];
    const int*   src   = (const int*)d_in[2];
    const int*   dst   = (const int*)d_in[3];
    const int*   rel   = (const int*)d_in[4];
    const float* basis = (const float*)d_in[5];
    const float* coeff = (const float*)d_in[6];
    const float* loopw = (const float*)d_in[7];
    float* out = (float*)d_out;

    const int N = in_sizes[1];       // 50000
    const int E = in_sizes[2];       // 800000
    const int R = in_sizes[6] / 4;   // 100

    const int nB    = (N + 255) >> 8;              // 196 coarse buckets
    const int nblkH = (E + EPB - 1) / EPB;         // 196 edge chunks

    char* ws = (char*)d_ws;
    size_t off = 0;
    auto walloc = [&](size_t bytes) -> char* {
        char* p = ws + off;
        off = (off + bytes + 255) & ~(size_t)255;
        return p;
    };
    unsigned short* A2     = (unsigned short*)walloc((size_t)N * 512 * 2);  // 51.2 MB
    unsigned short* hbf    = (unsigned short*)walloc((size_t)N * 128 * 2);  // 12.8 MB
    unsigned short* WT2    = (unsigned short*)walloc(128 * 640 * 2);
    int*            rowptr = (int*)walloc((size_t)(N + 1) * 4);
    int*            bcnt   = (int*)walloc((size_t)nB * 16 * 4);   // 64B-padded counters
    unsigned int*   tmp    = (unsigned int*)walloc((size_t)nB * MAXB * 4);  // 4.8 MB
    unsigned int*   sedge  = (unsigned int*)walloc((size_t)E * 4);

    const int nconv8  = N * 16;                    // 8 floats per thread
    const int nb_conv = (nconv8 + 1023) / 1024;    // 782

    hipMemsetAsync(bcnt, 0, (size_t)nB * 16 * 4, stream);
    prep_all<<<nb_conv + nblkH + 128, 1024, 0, stream>>>(
        h, hbf, nconv8, dst, src, rel, bcnt, tmp, E, nB, nblkH,
        basis, loopw, WT2, nb_conv);
    bucket_sort<<<nB, 1024, 0, stream>>>(tmp, bcnt, sedge, rowptr, E, N, nB);
    aggregate_pre<<<(N + 3) / 4, 256, 0, stream>>>(hbf, rowptr, sedge, coeff, norm, A2, N, R);
    final_gemm<<<(N + 127) / 128, 256, 0, stream>>>(A2, hbf, WT2, out, N);
}